// Round 10
// baseline (3132.770 us; speedup 1.0000x reference)
//
#include <hip/hip_runtime.h>
#include <hip/hip_bf16.h>
#include <math.h>

// Problem constants (fixed by setup_inputs)
#define BB 72      // G * SAMPLE_NUMS = 8*9
#define SS 512
#define HH 768
#define GG 8
#define SN 9
#define VR 2       // VIEW_RANGE
#define NCH 2
// ROUND 10: OUTPUT IS FP32, layout = return order [loss | q | a | n].
// Evidence: fp32 decode of our stray bf16 writes explains every prior error
// bit-exactly (stub 0.2451=|ref_loss|; r1/3/5/6 0.3467=|ref_loss-bf16(q00)|
// with q00=-0.1015625; r7 no-op = low-half write; r8/r9 = q01/a01 in word0).
// "(bf16, ref=np)" in the test label is hard-coded, not a dtype signal.
// Inputs fp32, documented dict order (r6: content-resolution == dict order).
// Pipeline: literal brute-force (the factorized variant becomes a later
// optimization + cross-check).

__device__ float g_cw[3 * BB * SS];
__device__ float g_nums[NCH * BB * 6 * HH];
__device__ float g_dens[BB * 3];
__device__ float g_logits[3 * BB];

__device__ __forceinline__ void class_masks(float am, int id, float& qv, float& av, float& nv) {
    qv = (id == 1 || id == 2) ? am : 0.0f;
    av = (id == 0 || id == 2) ? am : 0.0f;
    nv = (id == 3) ? am : 0.0f;
}

// Brute-force column weights: one block per (token t, batch b).
//   cw_c[t] = c_t * sum_s pair_c(s) * M[s,t] * band[s,t] * <x_s, x_t>
// M[s,t] = q_s(a_t+n_t) + a_s(q_t+n_t) + n_s(q_t+a_t).
__global__ void k_colw(const float* __restrict__ x, const float* __restrict__ am,
                       const int* __restrict__ qa, const int* __restrict__ turn) {
    __shared__ float xt[HH];
    __shared__ float red[4][3];
    const int t = blockIdx.x, b = blockIdx.y, tid = threadIdx.x;
    const float* xb = x + (size_t)b * SS * HH;
    for (int j = tid; j < HH; j += 256) xt[j] = xb[(size_t)t * HH + j];
    __syncthreads();

    const float amt = am[b * SS + t]; const int idt = qa[b * SS + t];
    float qt, at, nt; class_masks(amt, idt, qt, at, nt);
    const int trt = turn[b * SS + t];
    const float ant = at + nt, qnt = qt + nt, qat = qt + at;

    const int wave = tid >> 6, lane = tid & 63;
    float accq = 0, acca = 0, accn = 0;
    for (int s = wave; s < SS; s += 4) {
        int d = turn[b * SS + s] - trt; if (d < 0) d = -d;
        if (d > VR) continue;                      // wave-uniform branch
        const float* xs = xb + (size_t)s * HH;
        float g = 0;
        for (int h = lane; h < HH; h += 64) g += xs[h] * xt[h];
        for (int off = 32; off; off >>= 1) g += __shfl_xor(g, off);
        float ams = am[b * SS + s]; int ids = qa[b * SS + s];
        float qs, as_, ns; class_masks(ams, ids, qs, as_, ns);
        float M = qs * ant + as_ * qnt + ns * qat;
        float gm = g * M;
        accq += (as_ + ns) * gm;
        acca += (qs + ns) * gm;
        accn += (qs + as_) * gm;
    }
    if (lane == 0) { red[wave][0] = accq; red[wave][1] = acca; red[wave][2] = accn; }
    __syncthreads();
    if (tid == 0) {
        float Aq = 0, Aa = 0, An = 0;
        for (int w = 0; w < 4; ++w) { Aq += red[w][0]; Aa += red[w][1]; An += red[w][2]; }
        g_cw[0 * BB * SS + b * SS + t] = qt * Aq;
        g_cw[1 * BB * SS + b * SS + t] = at * Aa;
        g_cw[2 * BB * SS + b * SS + t] = nt * An;
    }
}

// Weighted sums over tokens -> 6 numerator vectors per batch.
__global__ void k_nums(const float* __restrict__ x, const float* __restrict__ am,
                       const int* __restrict__ qa) {
    const int hc = blockIdx.x, b = blockIdx.y, chunk = blockIdx.z;
    const int h = hc * 256 + threadIdx.x;
    const int sBeg = chunk * (SS / NCH), sEnd = sBeg + (SS / NCH);
    float sq = 0, sa = 0, sn = 0, cq = 0, ca = 0, cn = 0;
    for (int s = sBeg; s < sEnd; ++s) {
        float a = am[b * SS + s]; int id = qa[b * SS + s];
        float qv, av, nv; class_masks(a, id, qv, av, nv);
        float xv = x[(size_t)(b * SS + s) * HH + h];
        sq += xv * qv * qv; sa += xv * av * av; sn += xv * nv * nv;
        cq += xv * g_cw[0 * BB * SS + b * SS + s];
        ca += xv * g_cw[1 * BB * SS + b * SS + s];
        cn += xv * g_cw[2 * BB * SS + b * SS + s];
    }
    size_t base = ((size_t)(chunk * BB + b) * 6) * HH + h;
    g_nums[base + 0 * HH] = sq; g_nums[base + 1 * HH] = sa; g_nums[base + 2 * HH] = sn;
    g_nums[base + 3 * HH] = cq; g_nums[base + 4 * HH] = ca; g_nums[base + 5 * HH] = cn;
}

// Mask-sum denominators per batch
__global__ void k_dens(const float* __restrict__ am, const int* __restrict__ qa) {
    const int b = blockIdx.x, tid = threadIdx.x;
    float q = 0, a = 0, n = 0;
    for (int s = tid; s < SS; s += 256) {
        float m = am[b * SS + s]; int id = qa[b * SS + s];
        float qv, av, nv; class_masks(m, id, qv, av, nv);
        q += qv; a += av; n += nv;
    }
    for (int off = 32; off; off >>= 1) {
        q += __shfl_down(q, off); a += __shfl_down(a, off); n += __shfl_down(n, off);
    }
    __shared__ float red[4][3];
    int wave = tid >> 6, lane = tid & 63;
    if (lane == 0) { red[wave][0] = q; red[wave][1] = a; red[wave][2] = n; }
    __syncthreads();
    if (tid == 0) {
        float Q = 0, A = 0, N = 0;
        for (int w = 0; w < 4; ++w) { Q += red[w][0]; A += red[w][1]; N += red[w][2]; }
        g_dens[b * 3 + 0] = Q; g_dens[b * 3 + 1] = A; g_dens[b * 3 + 2] = N;
    }
}

// Cosine logits per (class c: 0=q,1=a,2=n); fp32 self-avg outputs for group
// sample 0 at out[1 + (c*GG + g)*HH + h]  (return order: loss,q,a,n).
__global__ void k_cos(float* __restrict__ out) {
    const int c = blockIdx.x, b = blockIdx.y, tid = threadIdx.x;
    float Dq = g_dens[b * 3 + 0], Da = g_dens[b * 3 + 1], Dn = g_dens[b * 3 + 2];
    float Dself = (c == 0) ? Dq : ((c == 1) ? Da : Dn);
    float Dcross = (c == 0) ? (Da + Dn) : ((c == 1) ? (Dq + Dn) : (Dq + Da));
    float invS = 1.0f / (Dself + 1e-6f), invC = 1.0f / (Dcross + 1e-6f);
    float dot = 0, n1 = 0, n2 = 0;
#pragma unroll
    for (int j = 0; j < 3; ++j) {
        int h = tid + j * 256;
        float sv = 0, cv = 0;
#pragma unroll
        for (int ch = 0; ch < NCH; ++ch) {
            size_t base = ((size_t)(ch * BB + b) * 6) * HH + h;
            sv += g_nums[base + (size_t)c * HH];
            cv += g_nums[base + (size_t)(3 + c) * HH];
        }
        sv *= invS; cv *= invC;
        dot += sv * cv; n1 += sv * sv; n2 += cv * cv;
        if (b % SN == 0)
            out[1 + ((size_t)c * GG + b / SN) * HH + h] = sv;
    }
    for (int off = 32; off; off >>= 1) {
        dot += __shfl_down(dot, off); n1 += __shfl_down(n1, off); n2 += __shfl_down(n2, off);
    }
    __shared__ float red[4][3];
    int wave = tid >> 6, lane = tid & 63;
    if (lane == 0) { red[wave][0] = dot; red[wave][1] = n1; red[wave][2] = n2; }
    __syncthreads();
    if (tid == 0) {
        float D = 0, N1 = 0, N2 = 0;
        for (int w = 0; w < 4; ++w) { D += red[w][0]; N1 += red[w][1]; N2 += red[w][2]; }
        float nx = fmaxf(sqrtf(N1), 1e-8f);
        float ny = fmaxf(sqrtf(N2), 1e-8f);
        float cc = D / (nx * ny);
        if (cc == 1.0f) cc = __uint_as_float(0x7FC00000u);
        g_logits[c * BB + b] = cc / 0.07f;
    }
}

// log_softmax + nanmean loss across 3 classes -> out[0] (fp32).
__global__ void k_loss(const float* __restrict__ labels, float* __restrict__ out) {
    __shared__ float rs[24];
    __shared__ int rc[24];
    const int tid = threadIdx.x;
    if (tid < 24) {
        int c = tid / GG, g = tid % GG;
        float lg[SN]; bool anynan = false;
        for (int j = 0; j < SN; ++j) {
            float v = g_logits[c * BB + g * SN + j];
            lg[j] = v;
            anynan = anynan || isnan(v);
        }
        float ssum = 0; int cnt = 0;
        if (!anynan) {
            float m = -1e30f;
            for (int j = 0; j < SN; ++j) m = fmaxf(m, lg[j]);
            float se = 0;
            for (int j = 0; j < SN; ++j) se += expf(lg[j] - m);
            float lse = m + logf(se);
            for (int j = 0; j < SN; ++j) ssum += (lg[j] - lse) * labels[g * SN + j];
            cnt = SN;
        }
        rs[tid] = ssum; rc[tid] = cnt;
    }
    __syncthreads();
    if (tid == 0) {
        float total = 0;
        for (int c = 0; c < 3; ++c) {
            float s = 0; int n = 0;
            for (int g = 0; g < GG; ++g) { s += rs[c * GG + g]; n += rc[c * GG + g]; }
            total += -(s / (float)n);
        }
        out[0] = total / 3.0f;
    }
}

extern "C" void kernel_launch(void* const* d_in, const int* in_sizes, int n_in,
                              void* d_out, int out_size, void* d_ws, size_t ws_size,
                              hipStream_t stream) {
    const float* x      = (const float*)d_in[0];
    const float* am     = (const float*)d_in[1];
    const float* labels = (const float*)d_in[2];
    const int*   qa     = (const int*)d_in[3];
    const int*   turn   = (const int*)d_in[4];
    float* out = (float*)d_out;

    k_colw<<<dim3(SS, BB), 256, 0, stream>>>(x, am, qa, turn);
    k_dens<<<dim3(BB),     256, 0, stream>>>(am, qa);
    k_nums<<<dim3(3, BB, NCH), 256, 0, stream>>>(x, am, qa);
    k_cos <<<dim3(3, BB),  256, 0, stream>>>(out);
    k_loss<<<dim3(1),      64,  0, stream>>>(labels, out);
}